// Round 3
// baseline (1601.487 us; speedup 1.0000x reference)
//
#include <hip/hip_runtime.h>
#include <math.h>

#define ND  256    // num_data (steps)
#define SEQ 2048
#define NI  256
#define NH  1024
#define NO  256

#define RB   64                 // recur blocks (all co-resident: 1 block/CU)
#define RT   1024               // recur threads (16 waves)
#define HPB  16                 // hidden units per block (NH / RB)
#define NHP  (NH + 1)           // padded LDS row (break 16-way write conflicts)

#define XTB  32                 // t-tile for xproj
#define OTB  8                  // t-tile for outproj

// relaxed agent-scope atomics: compile to sc0|sc1 ops that bypass/write-through
// L1+L2 to the device coherence point (IF) — no buffer_wbl2/buffer_inv needed.
#define ALF(p)   __hip_atomic_load((p), __ATOMIC_RELAXED, __HIP_MEMORY_SCOPE_AGENT)
#define ASF(p,v) __hip_atomic_store((p), (v), __ATOMIC_RELAXED, __HIP_MEMORY_SCOPE_AGENT)

// ---------------- input projections, t-tiled: X[t][h] = b[h] + x[t,2047,:]@W --
__global__ void xproj(const float* __restrict__ x,
                      const float* __restrict__ Win1, const float* __restrict__ b1,
                      const float* __restrict__ Win2, const float* __restrict__ b2,
                      float* __restrict__ X1, float* __restrict__ X2) {
    const int   layer = blockIdx.z;
    const int   t0    = blockIdx.y * XTB;
    const int   h     = blockIdx.x * 256 + threadIdx.x;
    const float* W = layer ? Win2 : Win1;
    const float* b = layer ? b2   : b1;
    float*       X = layer ? X2   : X1;

    __shared__ float lx[XTB][NI];          // 32 KB: last seq row for 32 t's
    for (int idx = threadIdx.x; idx < XTB * NI; idx += 256) {
        int r = idx >> 8, c = idx & (NI - 1);
        lx[r][c] = x[(size_t)(t0 + r) * SEQ * NI + (size_t)(SEQ - 1) * NI + c];
    }
    __syncthreads();

    float acc[XTB];
    float bias = b[h];
    #pragma unroll
    for (int r = 0; r < XTB; ++r) acc[r] = bias;

    for (int i = 0; i < NI; ++i) {
        float wv = W[i * NH + h];          // coalesced over h, L1/L2-cached
        #pragma unroll
        for (int r = 0; r < XTB; ++r) acc[r] += lx[r][i] * wv;
    }
    #pragma unroll
    for (int r = 0; r < XTB; ++r) X[(t0 + r) * NH + h] = acc[r];
}

// ---------------- sequential recurrence: 64 blocks, weights LDS-resident -----
// Per-step sync, fully wave-decoupled (ONE __syncthreads per step):
//   consumer: lane polls flag[owner(tid)] (owner = tid>>4), then loads its own
//             element back-to-back in the same wave. Each flag line is polled
//             by exactly one wave per block (64 streams/line — no storm).
//   producer: each wave drains its own stores (s_waitcnt 0), ds_adds a
//             per-parity LDS counter, and proceeds into step t+1 immediately.
//             tid0 spins on the LDS counter (no IF traffic) and raises flag[b].
// State is published as SEPARATE z1 / z2 streams; consumers form z12 = z1+z2
// themselves (same operands, same order => bit-identical to fused publish).
// sz1 ping-pongs on t&1 (reuse distance spans barrier B of t+1); sz2
// ping-pongs on the z2 generation (staged at odd steps, reuse distance 4).
__launch_bounds__(RT, 1)
__global__ void recur(const float* __restrict__ Wr1, const float* __restrict__ Wr2,
                      const float* __restrict__ X1,  const float* __restrict__ X2,
                      float* Z1b, float* Z2b, float* Z1hist, int* flags) {
    __shared__ float lW1[HPB][NHP];        // 64 KB (+pad)
    __shared__ float lW2[HPB][NHP];        // 64 KB (+pad)
    __shared__ float sz1[2][NH];           // 8 KB  z1 staging (ping on t&1)
    __shared__ float sz2[2][NH];           // 8 KB  z2 staging (ping on z2 gen)
    __shared__ int   cnt[2];               // per-parity publish counters

    const int tid = threadIdx.x;
    const int b   = blockIdx.x;
    const int h0  = b * HPB;

    if (tid < 2) cnt[tid] = 0;

    // one-time weight residency: consecutive tid -> consecutive h (64B chunks)
    for (int idx = tid; idx < HPB * NH; idx += RT) {
        int hw = idx & (HPB - 1);
        int k  = idx >> 4;                 // HPB == 16
        lW1[hw][k] = Wr1[(size_t)k * NH + h0 + hw];
        lW2[hw][k] = Wr2[(size_t)k * NH + h0 + hw];
    }
    __syncthreads();

    const int w     = tid >> 6;            // wave 0..15 <-> hidden unit
    const int l     = tid & 63;
    const int h     = h0 + w;
    const int owner = tid >> 4;            // block owning element tid

    for (int t = 0; t < ND; ++t) {
        const bool even   = (t & 1) == 0;
        const int  q      = t >> 1;
        const int  s2     = (t == 0) ? 0 : (even ? (q & 1) : ((q + 1) & 1));
        const bool stage2 = (t == 0) || !even;   // z2 gen changes after even steps

        // ---- consume: poll own element's owner, then load own element ----
        if (t != 0) {
            const int* fp = flags + owner * 32;  // one 128B line per block
            while (ALF(fp) < t) { }
        }
        asm volatile("" ::: "memory");           // loads stay after poll exit
        float z1v = ALF(Z1b + (t & 1) * NH + tid);
        float z2v = 0.0f;
        if (stage2) z2v = ALF(Z2b + s2 * NH + tid);
        sz1[t & 1][tid] = z1v;
        if (stage2) sz2[s2][tid] = z2v;
        __syncthreads();                   // B: the ONLY barrier per step

        float xv1 = X1[t * NH + h];        // cached broadcast loads
        float xv2 = even ? X2[t * NH + h] : 0.0f;

        const float* z1c = sz1[t & 1];
        const float* z2c = sz2[s2];
        float r1 = 0.0f, r2 = 0.0f;
        #pragma unroll
        for (int j = 0; j < 16; ++j) {
            int k = l + 64 * j;            // conflict-free LDS
            r1 += (z1c[k] + z2c[k]) * lW1[w][k];
        }
        if (even) {
            #pragma unroll
            for (int j = 0; j < 16; ++j) {
                int k = l + 64 * j;
                r2 += z2c[k] * lW2[w][k];
            }
        }
        #pragma unroll
        for (int off = 32; off; off >>= 1) {
            r1 += __shfl_xor(r1, off, 64);
            if (even) r2 += __shfl_xor(r2, off, 64);
        }

        // ---- publish ----
        if (l == 0) {
            float z1n = tanhf(xv1 + r1);
            Z1hist[t * NH + h] = z1n;      // plain cached store (read post-kernel)
            if (t < ND - 1) {
                ASF(Z1b + ((t + 1) & 1) * NH + h, z1n);
                if (even) {
                    float z2h = tanhf(xv2 + r2);
                    ASF(Z2b + ((q + 1) & 1) * NH + h, z2h);
                }
            }
        }

        if (t == ND - 1) break;

        __builtin_amdgcn_s_waitcnt(0);     // this wave's publishes at IF
        if (l == 0) atomicAdd(&cnt[t & 1], 1);
        if (tid == 0) {
            while (__hip_atomic_load(&cnt[t & 1], __ATOMIC_ACQUIRE,
                                     __HIP_MEMORY_SCOPE_WORKGROUP) != 16) { }
            cnt[(t & 1) ^ 1] = 0;          // reset counter for step t+2
            ASF(flags + b * 32, t + 1);    // all 16 waves' stores visible
        }
        // other 15 waves fall through into step t+1's poll immediately
    }
}

// ---------------- output projection, t-tiled: out[t] = tanh(z1[t]@Wout + b) --
__global__ void outproj(const float* __restrict__ Z1hist,
                        const float* __restrict__ Wout,
                        const float* __restrict__ bout,
                        float* __restrict__ out) {
    const int t0 = blockIdx.x * OTB;
    const int o  = threadIdx.x;

    __shared__ float lz[OTB][NH];          // 32 KB
    for (int idx = threadIdx.x; idx < OTB * NH; idx += 256) {
        int r = idx >> 10, c = idx & (NH - 1);
        lz[r][c] = Z1hist[(t0 + r) * NH + c];
    }
    __syncthreads();

    float acc[OTB];
    float bias = bout[o];
    #pragma unroll
    for (int r = 0; r < OTB; ++r) acc[r] = bias;

    for (int hh = 0; hh < NH; ++hh) {
        float wv = Wout[hh * NO + o];      // coalesced over o
        #pragma unroll
        for (int r = 0; r < OTB; ++r) acc[r] += lz[r][hh] * wv;
    }
    #pragma unroll
    for (int r = 0; r < OTB; ++r) out[(t0 + r) * NO + o] = tanhf(acc[r]);
}

extern "C" void kernel_launch(void* const* d_in, const int* in_sizes, int n_in,
                              void* d_out, int out_size, void* d_ws, size_t ws_size,
                              hipStream_t stream) {
    const float* x     = (const float*)d_in[0];
    const float* Win1  = (const float*)d_in[1];
    const float* b1    = (const float*)d_in[2];
    const float* Wr1   = (const float*)d_in[3];
    const float* Win2  = (const float*)d_in[4];
    const float* b2    = (const float*)d_in[5];
    const float* Wr2   = (const float*)d_in[6];
    const float* Wout  = (const float*)d_in[7];
    const float* bout  = (const float*)d_in[8];
    float* out = (float*)d_out;

    // workspace layout (floats)
    float* ws    = (float*)d_ws;
    float* Z1b   = ws;                      // 2*NH   ping-pong z1
    float* Z2b   = Z1b + 2 * NH;            // 2*NH   ping-pong z2 (even steps)
    int*   flags = (int*)(Z2b + 2 * NH);    // RB*32 ints (one 128B line/block)
    float* Z1h   = (float*)(flags + RB * 32); // ND*NH
    float* X1    = Z1h + ND * NH;           // ND*NH
    float* X2    = X1 + ND * NH;            // ND*NH

    // zero initial state + flags (ws is re-poisoned before every call)
    hipMemsetAsync(Z1b, 0, (4 * NH) * sizeof(float) + RB * 32 * sizeof(int), stream);

    dim3 xg(NH / 256, ND / XTB, 2);
    xproj<<<xg, 256, 0, stream>>>(x, Win1, b1, Win2, b2, X1, X2);

    recur<<<RB, RT, 0, stream>>>(Wr1, Wr2, X1, X2, Z1b, Z2b, Z1h, flags);

    outproj<<<ND / OTB, NO, 0, stream>>>(Z1h, Wout, bout, out);
}